// Round 16
// baseline (335.601 us; speedup 1.0000x reference)
//
#include <hip/hip_runtime.h>
#include <hip/hip_bf16.h>

#define S_DIM 128
#define N_PTS 384
#define CM    64
#define C_DIM 32
#define CZ    128
#define NC    (N_PTS*C_DIM)   // 12288

typedef __attribute__((ext_vector_type(8)))  __bf16 bf16x8;
typedef __attribute__((ext_vector_type(16))) float  f32x16;
typedef unsigned short u16;
typedef unsigned int   u32;

__device__ __forceinline__ bf16x8 lds_frag(const void* base, int byteoff){
  union { uint4 u; bf16x8 v; } x;
  x.u = *(const uint4*)((const char*)base + byteoff);
  return x.v;
}
__device__ __forceinline__ u32 pk2(float a, float b){
  __hip_bfloat162 h;
  h.x = (__hip_bfloat16)a;
  h.y = (__hip_bfloat16)b;
  union { __hip_bfloat162 h2; u32 u; } c; c.h2 = h;
  return c.u;
}

// ============ k_prep: merged {lnproj | wt | norm} ============
// grid 1024 x 512 thr: bid<384 lnproj(n=bid); <640 wt; else norm(i=bid-640)
// A_ws/B_ws written PRE-SWIZZLED: byte at row*256 + (kb ^ ((row&15)<<4)) holds (row, kb)
__global__ __launch_bounds__(512) void k_prep(
    const float* __restrict__ msa, const float* __restrict__ mask,
    const float* __restrict__ gamma, const float* __restrict__ beta,
    const float* __restrict__ wa, const float* __restrict__ wb,
    const float* __restrict__ w_out,
    __hip_bfloat16* __restrict__ A_ws, __hip_bfloat16* __restrict__ B_ws,
    __hip_bfloat16* __restrict__ wt, float* __restrict__ nrm_g){
  __shared__ union {
    u16   X[128*64];     // 16KB bf16 LN'd [s][m]
    float T[64*128];     // 32KB f32 [col][s]
  } sh;
  __shared__ float ln_mk[128];

  const int bid = blockIdx.x, tid = threadIdx.x;

  if (bid >= 640){                 // ---- norm ----
    int i = bid - 640, j = tid;
    if (j < N_PTS){
      float a = 0.f;
      #pragma unroll 8
      for (int s = 0; s < S_DIM; ++s)
        a += mask[s*N_PTS + i] * mask[s*N_PTS + j];
      nrm_g[i*N_PTS + j] = a;
    }
    return;
  }
  if (bid >= 384){                 // ---- wt permute ----
    int o = (bid - 384)*512 + tid;     // 131072 total
    int z = o >> 10, mi = o & 1023;
    int e = mi & 7, j = (mi >> 3) & 3, hi = (mi >> 5) & 1, Q = mi >> 6;
    int ks = Q*4 + j;
    int pos = ks*16 + hi*8 + e;
    int c = ((pos >> 7) << 2) | (pos & 3);
    int d = (pos >> 2) & 31;
    int k = c*32 + d;
    wt[o] = (__hip_bfloat16)w_out[k*CZ + z];
    return;
  }

  // ---- lnproj (n = bid) ----
  const int w = tid >> 6, l = tid & 63;
  const int hi = l >> 5, ln = l & 31;
  const int n = bid;

  if (tid < 128) ln_mk[tid] = mask[tid*N_PTS + n];

  const float g  = gamma[l];
  const float be = beta[l];

  #pragma unroll
  for (int t = 0; t < 16; ++t){
    int s = w*16 + t;
    float x = msa[((size_t)s*N_PTS + n)*CM + l];
    float sum = x;
    #pragma unroll
    for (int m = 1; m < 64; m <<= 1) sum += __shfl_xor(sum, m, 64);
    float mu = sum * (1.0f/64.0f);
    float dx = x - mu;
    float vs = dx*dx;
    #pragma unroll
    for (int m = 1; m < 64; m <<= 1) vs += __shfl_xor(vs, m, 64);
    float rstd = rsqrtf(vs*(1.0f/64.0f) + 1e-5f);
    float xn = dx*rstd*g + be;
    __hip_bfloat16 hx = (__hip_bfloat16)xn;
    *(u16*)((char*)sh.X + s*128 + ((l*2) ^ ((s&7)<<4))) = *(u16*)&hx;
  }
  __syncthreads();

  const int mb = w >> 1, mat = w & 1;
  const float* W = mat ? wb : wa;
  f32x16 pacc;
  #pragma unroll
  for (int r = 0; r < 16; ++r) pacc[r] = 0.f;
  #pragma unroll
  for (int ks = 0; ks < 4; ++ks){
    int srow = mb*32 + ln;
    bf16x8 aF = lds_frag(sh.X, srow*128 + (((ks*32 + hi*16)) ^ ((srow&7)<<4)));
    union { u32 u[4]; bf16x8 v; } bx;
    #pragma unroll
    for (int e = 0; e < 4; ++e){
      int m = ks*16 + hi*8 + e*2;
      bx.u[e] = pk2(W[m*C_DIM + ln], W[(m+1)*C_DIM + ln]);
    }
    pacc = __builtin_amdgcn_mfma_f32_32x32x16_bf16(aF, bx.v, pacc, 0, 0, 0);
  }
  __syncthreads();

  const int col = mat*32 + ln;
  #pragma unroll
  for (int r = 0; r < 16; ++r){
    int rr = (r & 3) + ((r >> 2) << 3) + (hi << 2);
    int s = mb*32 + rr;
    *(float*)((char*)sh.T + col*512 + ((s*4) ^ ((col&7)<<4))) = pacc[r] * ln_mk[s];
  }
  __syncthreads();

  {
    int col2 = tid >> 3, sc = tid & 7;
    __hip_bfloat16* O = (col2 < 32) ? A_ws : B_ws;
    int row = n*C_DIM + (col2 & 31);
    uint4 pk_0, pk_1;
    u32* pw0 = (u32*)&pk_0;
    u32* pw1 = (u32*)&pk_1;
    #pragma unroll
    for (int q = 0; q < 4; ++q){
      union { uint4 u4; float f[4]; } rd;
      rd.u4 = *(const uint4*)((const char*)sh.T + col2*512 + ((sc*64 + q*16) ^ ((col2&7)<<4)));
      u32 a = pk2(rd.f[0], rd.f[1]);
      u32 b = pk2(rd.f[2], rd.f[3]);
      if (q < 2){ pw0[q*2] = a; pw0[q*2+1] = b; }
      else      { pw1[(q-2)*2] = a; pw1[(q-2)*2+1] = b; }
    }
    // pre-swizzled dst (slab byte image == LDS slab image)
    int swz = (row & 15) << 4;
    *(uint4*)((char*)O + (size_t)row*256 + ((sc*32)      ^ swz)) = pk_0;
    *(uint4*)((char*)O + (size_t)row*256 + ((sc*32 + 16) ^ swz)) = pk_1;
  }
}

// ============ k_fused: persistent (9 tiles/block); A re-staged EVERY tile (P aliases A!) ======
// grid 256, 512 threads (8 waves). Tile t = b*9+it: bi=t/48, bj=t%48.
// Stage B: waves (wr,wc) 2x4, 256x256 over K=128.
// Stage C: waves (kh, cc); M=64 (zc0/zc1); wreg[16] 4-round lookahead; symmetric reduce.
// pfB[8]: B(t+1) issued at stage-C round 3, written to LDS at next tile start.
__global__ __launch_bounds__(512, 2) void k_fused(
    const __hip_bfloat16* __restrict__ A_ws, const __hip_bfloat16* __restrict__ B_ws,
    const __hip_bfloat16* __restrict__ Wt,  const float* __restrict__ b_out,
    const float* __restrict__ nrm_g, float* __restrict__ out){
  __shared__ union {
    struct { u16 A[256*128]; u16 B[256*128]; } s1;   // 64KB + 64KB slabs (pre-swizzled image)
    struct { u16 P[64*1024]; } s2;                   // 128KB P (aliases A+B!)
  } sh;
  __shared__ float nrm[64];

  const int tid = threadIdx.x;
  const int w = tid >> 6, l = tid & 63;
  const int hi = l >> 5, ln = l & 31;
  const int kh = w >> 2, cc = w & 3;      // stage-C role
  const int wr = w >> 2, wc = w & 3;      // stage-B role
  const int b = blockIdx.x;

  char* shA = (char*)sh.s1.A;
  char* shB = (char*)sh.s1.B;
  char* shP = (char*)sh.s2.P;

  const char* wbase = (const char*)Wt + (size_t)(cc*32 + ln)*2048 + kh*1024 + hi*64;
  const float bo = b_out[cc*32 + ln];
  const int sw2 = (ln & 15) << 4;
  const int kbase = kh*1024;
  const char* prow0 = shP + (size_t)ln*2048;
  const char* prow1 = shP + (size_t)(32 + ln)*2048;

  // initial B prefetch for tile it=0
  uint4 pfB[8];
  {
    const char* Bg = (const char*)B_ws + (size_t)((b*9) % 48)*65536;
    #pragma unroll
    for (int q = 0; q < 8; ++q) pfB[q] = *(const uint4*)(Bg + (q*512 + tid)*16);
  }
  uint4 wreg[16];

  #pragma unroll 1
  for (int it = 0; it < 9; ++it){
    const int t = b*9 + it;
    const int bi = t/48, bj = t%48;

    // ---- stage slabs: A direct (issue loads first), B from prefetch regs ----
    const char* Ag = (const char*)A_ws + (size_t)bi*65536;
    uint4 tA[8];
    #pragma unroll
    for (int q = 0; q < 8; ++q) tA[q] = *(const uint4*)(Ag + (q*512 + tid)*16);
    #pragma unroll
    for (int q = 0; q < 8; ++q)
      *(uint4*)(shB + (q*512 + tid)*16) = pfB[q];
    #pragma unroll
    for (int q = 0; q < 8; ++q)
      *(uint4*)(shA + (q*512 + tid)*16) = tA[q];

    if (tid < 64){
      int i = bi*8 + (tid >> 3), jj = bj*8 + (tid & 7);
      nrm[tid] = nrm_g[i*N_PTS + jj];
    }
    #pragma unroll
    for (int u = 0; u < 8; ++u)
      wreg[u] = *(const uint4*)(wbase + (u>>2)*128 + (u&3)*16);
    __syncthreads();                       // B1: slabs ready

    // ---- stage B (no setprio: lockstep regime) ----
    f32x16 acc[4][2];
    #pragma unroll
    for (int mb = 0; mb < 4; ++mb)
      #pragma unroll
      for (int nb = 0; nb < 2; ++nb)
        #pragma unroll
        for (int r = 0; r < 16; ++r) acc[mb][nb][r] = 0.f;

    #pragma unroll
    for (int ks = 0; ks < 8; ++ks){
      const int k0b = ks*32 + hi*16;
      bf16x8 aF[4], bF[2];
      #pragma unroll
      for (int mb = 0; mb < 4; ++mb){
        int m = wr*128 + mb*32 + ln;
        aF[mb] = lds_frag(shA, m*256 + (k0b ^ ((m & 15) << 4)));
      }
      #pragma unroll
      for (int nb = 0; nb < 2; ++nb){
        int n = wc*64 + nb*32 + ln;
        bF[nb] = lds_frag(shB, n*256 + (k0b ^ ((n & 15) << 4)));
      }
      #pragma unroll
      for (int mb = 0; mb < 4; ++mb)
        #pragma unroll
        for (int nb = 0; nb < 2; ++nb)
          acc[mb][nb] = __builtin_amdgcn_mfma_f32_32x32x16_bf16(aF[mb], bF[nb], acc[mb][nb], 0, 0, 0);
    }
    __syncthreads();                       // B2: slab reads done

    // ---- wreg banks 2,3 + write P ----
    #pragma unroll
    for (int u = 8; u < 16; ++u)
      wreg[u] = *(const uint4*)(wbase + (u>>2)*128 + (u&3)*16);
    #pragma unroll
    for (int mb = 0; mb < 4; ++mb)
      #pragma unroll
      for (int nb = 0; nb < 2; ++nb){
        int p = (wr*4 + mb)*8 + (wc*2 + nb);
        int base = p*2048, sw = (p & 15) << 4;
        #pragma unroll
        for (int g = 0; g < 4; ++g){
          uint2 v;
          v.x = pk2(acc[mb][nb][4*g + 0], acc[mb][nb][4*g + 1]);
          v.y = pk2(acc[mb][nb][4*g + 2], acc[mb][nb][4*g + 3]);
          int off = ((2*g + hi)*256 + ln*8) ^ sw;
          *(uint2*)(shP + base + off) = v;
        }
      }
    __syncthreads();                       // B3: P ready

    // ---- stage C: partials over K-half kh; prefetch B(t+1) after round 3 ----
    f32x16 zc0, zc1;
    #pragma unroll
    for (int r = 0; r < 16; ++r){ zc0[r] = 0.f; zc1[r] = 0.f; }

    #pragma unroll
    for (int rd = 0; rd < 8; ++rd){
      bf16x8 a0[4], a1[4];
      #pragma unroll
      for (int u = 0; u < 4; ++u){
        int off = (kbase + (rd*4 + u)*32 + hi*16) ^ sw2;
        a0[u] = lds_frag(prow0, off);
        a1[u] = lds_frag(prow1, off);
      }
      __builtin_amdgcn_s_setprio(1);
      #pragma unroll
      for (int u = 0; u < 4; ++u){
        union { uint4 q; bf16x8 v; } bx; bx.q = wreg[(rd & 3)*4 + u];
        zc0 = __builtin_amdgcn_mfma_f32_32x32x16_bf16(a0[u], bx.v, zc0, 0, 0, 0);
        zc1 = __builtin_amdgcn_mfma_f32_32x32x16_bf16(a1[u], bx.v, zc1, 0, 0, 0);
      }
      __builtin_amdgcn_s_setprio(0);
      if (rd < 4){
        #pragma unroll
        for (int u = 0; u < 4; ++u)
          wreg[(rd & 3)*4 + u] = *(const uint4*)(wbase + (rd + 4)*128 + u*16);
      }
      if (rd == 3 && it < 8){
        const char* Bg2 = (const char*)B_ws + (size_t)((t + 1) % 48)*65536;
        #pragma unroll
        for (int q = 0; q < 8; ++q)
          pfB[q] = *(const uint4*)(Bg2 + (q*512 + tid)*16);
      }
    }
    __syncthreads();                       // B4: P reads done; P space free

    // ---- symmetric cross-kh reduce ----
    float* red0 = (float*)sh.s2.P;            // p 0..31 partials (written by kh=1)
    float* red1 = (float*)sh.s2.P + 32*128;   // p 32..63 partials (written by kh=0)
    if (kh == 0){
      #pragma unroll
      for (int r = 0; r < 16; ++r){
        int pr = (r & 3) + ((r >> 2) << 3) + (hi << 2);
        red1[pr*128 + cc*32 + ln] = zc1[r];
      }
    } else {
      #pragma unroll
      for (int r = 0; r < 16; ++r){
        int pr = (r & 3) + ((r >> 2) << 3) + (hi << 2);
        red0[pr*128 + cc*32 + ln] = zc0[r];
      }
    }
    __syncthreads();                       // B5: partials exchanged
    {
      const int z = cc*32 + ln;
      if (kh == 0){
        #pragma unroll
        for (int r = 0; r < 16; ++r){
          int pr = (r & 3) + ((r >> 2) << 3) + (hi << 2);
          float v = (zc0[r] + red0[pr*128 + z] + bo) / (nrm[pr] + 0.001f);
          int i = bi*8 + (pr >> 3), j = bj*8 + (pr & 7);
          out[((size_t)i*N_PTS + j)*CZ + z] = v;
        }
      } else {
        #pragma unroll
        for (int r = 0; r < 16; ++r){
          int pr = (r & 3) + ((r >> 2) << 3) + (hi << 2);
          int p = 32 + pr;
          float v = (zc1[r] + red1[pr*128 + z] + bo) / (nrm[p] + 0.001f);
          int i = bi*8 + (p >> 3), j = bj*8 + (p & 7);
          out[((size_t)i*N_PTS + j)*CZ + z] = v;
        }
      }
    }
    __syncthreads();                       // B6: red reads done before next slab write
  }
}

extern "C" void kernel_launch(void* const* d_in, const int* in_sizes, int n_in,
                              void* d_out, int out_size, void* d_ws, size_t ws_size,
                              hipStream_t stream) {
  (void)in_sizes; (void)n_in; (void)out_size; (void)ws_size;
  const float* msa   = (const float*)d_in[0];
  const float* mask  = (const float*)d_in[1];
  const float* gamma = (const float*)d_in[2];
  const float* beta  = (const float*)d_in[3];
  const float* wa    = (const float*)d_in[4];
  const float* wb    = (const float*)d_in[5];
  const float* wout  = (const float*)d_in[6];
  const float* bout  = (const float*)d_in[7];

  __hip_bfloat16* A_ws = (__hip_bfloat16*)d_ws;              // [12288][128] bf16 (pre-swizzled slabs)
  __hip_bfloat16* B_ws = A_ws + (size_t)NC*S_DIM;            // [12288][128] bf16 (pre-swizzled slabs)
  __hip_bfloat16* Wt   = B_ws + (size_t)NC*S_DIM;            // [128][1024] bf16 (pos-permuted)
  float* nrm_g = (float*)(Wt + (size_t)CZ*1024);             // [384][384] f32
  float* outp  = (float*)d_out;                              // [384][384][128] f32

  k_prep<<<1024, 512, 0, stream>>>(msa, mask, gamma, beta, wa, wb, wout,
                                   A_ws, B_ws, Wt, nrm_g);
  k_fused<<<256, 512, 0, stream>>>(A_ws, B_ws, Wt, bout, nrm_g, outp);
}

// Round 17
// 124.316 us; speedup vs baseline: 2.6996x; 2.6996x over previous
//
#include <hip/hip_runtime.h>
#include <hip/hip_bf16.h>

#define S_DIM 128
#define N_PTS 384
#define CM    64
#define C_DIM 32
#define CZ    128
#define NC    (N_PTS*C_DIM)   // 12288

typedef __attribute__((ext_vector_type(8)))  __bf16 bf16x8;
typedef __attribute__((ext_vector_type(16))) float  f32x16;
typedef unsigned short u16;
typedef unsigned int   u32;

__device__ __forceinline__ bf16x8 lds_frag(const void* base, int byteoff){
  union { uint4 u; bf16x8 v; } x;
  x.u = *(const uint4*)((const char*)base + byteoff);
  return x.v;
}
__device__ __forceinline__ u32 pk2(float a, float b){
  __hip_bfloat162 h;
  h.x = (__hip_bfloat16)a;
  h.y = (__hip_bfloat16)b;
  union { __hip_bfloat162 h2; u32 u; } c; c.h2 = h;
  return c.u;
}

// ============ k_prep: merged {lnproj | wt | norm} ============
// grid 1024 x 512 thr: bid<384 lnproj(n=bid); <640 wt; else norm(i=bid-640)
// A_ws/B_ws written PRE-SWIZZLED: byte at row*256 + (kb ^ ((row&15)<<4)) holds (row, kb)
__global__ __launch_bounds__(512) void k_prep(
    const float* __restrict__ msa, const float* __restrict__ mask,
    const float* __restrict__ gamma, const float* __restrict__ beta,
    const float* __restrict__ wa, const float* __restrict__ wb,
    const float* __restrict__ w_out,
    __hip_bfloat16* __restrict__ A_ws, __hip_bfloat16* __restrict__ B_ws,
    __hip_bfloat16* __restrict__ wt, float* __restrict__ nrm_g){
  __shared__ union {
    u16   X[128*64];     // 16KB bf16 LN'd [s][m]
    float T[64*128];     // 32KB f32 [col][s]
  } sh;
  __shared__ float ln_mk[128];

  const int bid = blockIdx.x, tid = threadIdx.x;

  if (bid >= 640){                 // ---- norm ----
    int i = bid - 640, j = tid;
    if (j < N_PTS){
      float a = 0.f;
      #pragma unroll 8
      for (int s = 0; s < S_DIM; ++s)
        a += mask[s*N_PTS + i] * mask[s*N_PTS + j];
      nrm_g[i*N_PTS + j] = a;
    }
    return;
  }
  if (bid >= 384){                 // ---- wt permute ----
    int o = (bid - 384)*512 + tid;     // 131072 total
    int z = o >> 10, mi = o & 1023;
    int e = mi & 7, j = (mi >> 3) & 3, hi = (mi >> 5) & 1, Q = mi >> 6;
    int ks = Q*4 + j;
    int pos = ks*16 + hi*8 + e;
    int c = ((pos >> 7) << 2) | (pos & 3);
    int d = (pos >> 2) & 31;
    int k = c*32 + d;
    wt[o] = (__hip_bfloat16)w_out[k*CZ + z];
    return;
  }

  // ---- lnproj (n = bid) ----
  const int w = tid >> 6, l = tid & 63;
  const int hi = l >> 5, ln = l & 31;
  const int n = bid;

  if (tid < 128) ln_mk[tid] = mask[tid*N_PTS + n];

  const float g  = gamma[l];
  const float be = beta[l];

  #pragma unroll
  for (int t = 0; t < 16; ++t){
    int s = w*16 + t;
    float x = msa[((size_t)s*N_PTS + n)*CM + l];
    float sum = x;
    #pragma unroll
    for (int m = 1; m < 64; m <<= 1) sum += __shfl_xor(sum, m, 64);
    float mu = sum * (1.0f/64.0f);
    float dx = x - mu;
    float vs = dx*dx;
    #pragma unroll
    for (int m = 1; m < 64; m <<= 1) vs += __shfl_xor(vs, m, 64);
    float rstd = rsqrtf(vs*(1.0f/64.0f) + 1e-5f);
    float xn = dx*rstd*g + be;
    __hip_bfloat16 hx = (__hip_bfloat16)xn;
    *(u16*)((char*)sh.X + s*128 + ((l*2) ^ ((s&7)<<4))) = *(u16*)&hx;
  }
  __syncthreads();

  const int mb = w >> 1, mat = w & 1;
  const float* W = mat ? wb : wa;
  f32x16 pacc;
  #pragma unroll
  for (int r = 0; r < 16; ++r) pacc[r] = 0.f;
  #pragma unroll
  for (int ks = 0; ks < 4; ++ks){
    int srow = mb*32 + ln;
    bf16x8 aF = lds_frag(sh.X, srow*128 + (((ks*32 + hi*16)) ^ ((srow&7)<<4)));
    union { u32 u[4]; bf16x8 v; } bx;
    #pragma unroll
    for (int e = 0; e < 4; ++e){
      int m = ks*16 + hi*8 + e*2;
      bx.u[e] = pk2(W[m*C_DIM + ln], W[(m+1)*C_DIM + ln]);
    }
    pacc = __builtin_amdgcn_mfma_f32_32x32x16_bf16(aF, bx.v, pacc, 0, 0, 0);
  }
  __syncthreads();

  const int col = mat*32 + ln;
  #pragma unroll
  for (int r = 0; r < 16; ++r){
    int rr = (r & 3) + ((r >> 2) << 3) + (hi << 2);
    int s = mb*32 + rr;
    *(float*)((char*)sh.T + col*512 + ((s*4) ^ ((col&7)<<4))) = pacc[r] * ln_mk[s];
  }
  __syncthreads();

  {
    int col2 = tid >> 3, sc = tid & 7;
    __hip_bfloat16* O = (col2 < 32) ? A_ws : B_ws;
    int row = n*C_DIM + (col2 & 31);
    uint4 pk_0, pk_1;
    u32* pw0 = (u32*)&pk_0;
    u32* pw1 = (u32*)&pk_1;
    #pragma unroll
    for (int q = 0; q < 4; ++q){
      union { uint4 u4; float f[4]; } rd;
      rd.u4 = *(const uint4*)((const char*)sh.T + col2*512 + ((sc*64 + q*16) ^ ((col2&7)<<4)));
      u32 a = pk2(rd.f[0], rd.f[1]);
      u32 b = pk2(rd.f[2], rd.f[3]);
      if (q < 2){ pw0[q*2] = a; pw0[q*2+1] = b; }
      else      { pw1[(q-2)*2] = a; pw1[(q-2)*2+1] = b; }
    }
    // pre-swizzled dst (slab byte image == LDS slab image)
    int swz = (row & 15) << 4;
    *(uint4*)((char*)O + (size_t)row*256 + ((sc*32)      ^ swz)) = pk_0;
    *(uint4*)((char*)O + (size_t)row*256 + ((sc*32 + 16) ^ swz)) = pk_1;
  }
}

// ============ k_fused: R14 (best) + reciprocal-precompute epilogue ============
// grid (48,48), 512 threads (8 waves).
// Stage B: waves (wr,wc) 2x4, 256x256 over K=128.
// Stage C: waves (kh, cc); M=64 (zc0/zc1); wreg[16] 4-round lookahead; symmetric reduce.
__global__ __launch_bounds__(512, 2) void k_fused(
    const __hip_bfloat16* __restrict__ A_ws, const __hip_bfloat16* __restrict__ B_ws,
    const __hip_bfloat16* __restrict__ Wt,  const float* __restrict__ b_out,
    const float* __restrict__ nrm_g, float* __restrict__ out){
  __shared__ union {
    struct { u16 A[256*128]; u16 B[256*128]; } s1;   // 64KB + 64KB slabs (pre-swizzled image)
    struct { u16 P[64*1024]; } s2;                   // 128KB P (pos layout, swizzled)
  } sh;
  __shared__ float nrm[64];                          // holds 1/(norm+0.001)

  const int tid = threadIdx.x;
  const int w = tid >> 6, l = tid & 63;
  const int hi = l >> 5, ln = l & 31;
  const int bi = blockIdx.x, bj = blockIdx.y;

  // ---- staging: pure linear 16B copies (swizzle baked into global image) ----
  char* shA = (char*)sh.s1.A;
  char* shB = (char*)sh.s1.B;
  const char* Ag = (const char*)A_ws + (size_t)bi*65536;
  const char* Bg = (const char*)B_ws + (size_t)bj*65536;
  #pragma unroll
  for (int it = 0; it < 8; ++it){
    int o = (it*512 + tid) * 16;
    *(uint4*)(shA + o) = *(const uint4*)(Ag + o);
    *(uint4*)(shB + o) = *(const uint4*)(Bg + o);
  }

  // ---- early stage-C prefetch: inv-nrm + wreg banks 0,1 ----
  if (tid < 64){
    int i = bi*8 + (tid >> 3), jj = bj*8 + (tid & 7);
    nrm[tid] = 1.0f / (nrm_g[i*N_PTS + jj] + 0.001f);
  }
  const int kh = w >> 2, cc = w & 3;      // stage-C role
  const char* wbase = (const char*)Wt + (size_t)(cc*32 + ln)*2048 + kh*1024 + hi*64;
  uint4 wreg[16];
  #pragma unroll
  for (int u = 0; u < 8; ++u)
    wreg[u] = *(const uint4*)(wbase + (u>>2)*128 + (u&3)*16);
  __syncthreads();

  // ---- stage B (no setprio: lockstep regime, m190) ----
  const int wr = w >> 2, wc = w & 3;
  f32x16 acc[4][2];
  #pragma unroll
  for (int mb = 0; mb < 4; ++mb)
    #pragma unroll
    for (int nb = 0; nb < 2; ++nb)
      #pragma unroll
      for (int r = 0; r < 16; ++r) acc[mb][nb][r] = 0.f;

  #pragma unroll
  for (int ks = 0; ks < 8; ++ks){
    const int k0b = ks*32 + hi*16;
    bf16x8 aF[4], bF[2];
    #pragma unroll
    for (int mb = 0; mb < 4; ++mb){
      int m = wr*128 + mb*32 + ln;
      aF[mb] = lds_frag(shA, m*256 + (k0b ^ ((m & 15) << 4)));
    }
    #pragma unroll
    for (int nb = 0; nb < 2; ++nb){
      int n = wc*64 + nb*32 + ln;
      bF[nb] = lds_frag(shB, n*256 + (k0b ^ ((n & 15) << 4)));
    }
    #pragma unroll
    for (int mb = 0; mb < 4; ++mb)
      #pragma unroll
      for (int nb = 0; nb < 2; ++nb)
        acc[mb][nb] = __builtin_amdgcn_mfma_f32_32x32x16_bf16(aF[mb], bF[nb], acc[mb][nb], 0, 0, 0);
  }
  __syncthreads();

  // ---- write P (pos layout, cvt_pk packed); load wreg banks 2,3 in parallel ----
  char* shP = (char*)sh.s2.P;
  #pragma unroll
  for (int u = 8; u < 16; ++u)
    wreg[u] = *(const uint4*)(wbase + (u>>2)*128 + (u&3)*16);
  #pragma unroll
  for (int mb = 0; mb < 4; ++mb)
    #pragma unroll
    for (int nb = 0; nb < 2; ++nb){
      int p = (wr*4 + mb)*8 + (wc*2 + nb);
      int base = p*2048, sw = (p & 15) << 4;
      #pragma unroll
      for (int g = 0; g < 4; ++g){
        uint2 v;
        v.x = pk2(acc[mb][nb][4*g + 0], acc[mb][nb][4*g + 1]);
        v.y = pk2(acc[mb][nb][4*g + 2], acc[mb][nb][4*g + 3]);
        int off = ((2*g + hi)*256 + ln*8) ^ sw;
        *(uint2*)(shP + base + off) = v;
      }
    }
  __syncthreads();

  // ---- stage C: z[p][z'] partials over K-half kh; M=64 (zc0: p=ln, zc1: p=32+ln) ----
  f32x16 zc0, zc1;
  #pragma unroll
  for (int r = 0; r < 16; ++r){ zc0[r] = 0.f; zc1[r] = 0.f; }

  const char* prow0 = shP + (size_t)ln*2048;
  const char* prow1 = shP + (size_t)(32 + ln)*2048;
  const int sw2 = (ln & 15) << 4;
  const int kbase = kh*1024;

  #pragma unroll
  for (int rd = 0; rd < 8; ++rd){
    bf16x8 a0[4], a1[4];
    #pragma unroll
    for (int u = 0; u < 4; ++u){
      int off = (kbase + (rd*4 + u)*32 + hi*16) ^ sw2;
      a0[u] = lds_frag(prow0, off);
      a1[u] = lds_frag(prow1, off);
    }
    __builtin_amdgcn_s_setprio(1);
    #pragma unroll
    for (int u = 0; u < 4; ++u){
      union { uint4 q; bf16x8 v; } bx; bx.q = wreg[(rd & 3)*4 + u];
      zc0 = __builtin_amdgcn_mfma_f32_32x32x16_bf16(a0[u], bx.v, zc0, 0, 0, 0);
      zc1 = __builtin_amdgcn_mfma_f32_32x32x16_bf16(a1[u], bx.v, zc1, 0, 0, 0);
    }
    __builtin_amdgcn_s_setprio(0);
    // refill consumed bank for round rd+4 (distance ~3 rounds > L2 latency)
    if (rd < 4){
      #pragma unroll
      for (int u = 0; u < 4; ++u)
        wreg[(rd & 3)*4 + u] = *(const uint4*)(wbase + (rd + 4)*128 + u*16);
    }
  }
  __syncthreads();   // all P reads complete; P space free

  // ---- symmetric cross-kh reduce: each half exchanges the p-range it does NOT store ----
  float* red0 = (float*)sh.s2.P;            // p 0..31 partials (written by kh=1)
  float* red1 = (float*)sh.s2.P + 32*128;   // p 32..63 partials (written by kh=0)
  if (kh == 0){
    #pragma unroll
    for (int r = 0; r < 16; ++r){
      int pr = (r & 3) + ((r >> 2) << 3) + (hi << 2);
      red1[pr*128 + cc*32 + ln] = zc1[r];
    }
  } else {
    #pragma unroll
    for (int r = 0; r < 16; ++r){
      int pr = (r & 3) + ((r >> 2) << 3) + (hi << 2);
      red0[pr*128 + cc*32 + ln] = zc0[r];
    }
  }
  __syncthreads();
  {
    const int z = cc*32 + ln;
    const float bo = b_out[z];
    if (kh == 0){
      #pragma unroll
      for (int r = 0; r < 16; ++r){
        int pr = (r & 3) + ((r >> 2) << 3) + (hi << 2);
        float v = (zc0[r] + red0[pr*128 + z] + bo) * nrm[pr];
        int i = bi*8 + (pr >> 3), j = bj*8 + (pr & 7);
        out[((size_t)i*N_PTS + j)*CZ + z] = v;
      }
    } else {
      #pragma unroll
      for (int r = 0; r < 16; ++r){
        int pr = (r & 3) + ((r >> 2) << 3) + (hi << 2);
        int p = 32 + pr;
        float v = (zc1[r] + red1[pr*128 + z] + bo) * nrm[p];
        int i = bi*8 + (p >> 3), j = bj*8 + (p & 7);
        out[((size_t)i*N_PTS + j)*CZ + z] = v;
      }
    }
  }
}

extern "C" void kernel_launch(void* const* d_in, const int* in_sizes, int n_in,
                              void* d_out, int out_size, void* d_ws, size_t ws_size,
                              hipStream_t stream) {
  (void)in_sizes; (void)n_in; (void)out_size; (void)ws_size;
  const float* msa   = (const float*)d_in[0];
  const float* mask  = (const float*)d_in[1];
  const float* gamma = (const float*)d_in[2];
  const float* beta  = (const float*)d_in[3];
  const float* wa    = (const float*)d_in[4];
  const float* wb    = (const float*)d_in[5];
  const float* wout  = (const float*)d_in[6];
  const float* bout  = (const float*)d_in[7];

  __hip_bfloat16* A_ws = (__hip_bfloat16*)d_ws;              // [12288][128] bf16 (pre-swizzled slabs)
  __hip_bfloat16* B_ws = A_ws + (size_t)NC*S_DIM;            // [12288][128] bf16 (pre-swizzled slabs)
  __hip_bfloat16* Wt   = B_ws + (size_t)NC*S_DIM;            // [128][1024] bf16 (pos-permuted)
  float* nrm_g = (float*)(Wt + (size_t)CZ*1024);             // [384][384] f32
  float* outp  = (float*)d_out;                              // [384][384][128] f32

  k_prep<<<1024, 512, 0, stream>>>(msa, mask, gamma, beta, wa, wb, wout,
                                   A_ws, B_ws, Wt, nrm_g);
  dim3 g2(48, 48, 1);
  k_fused<<<g2, 512, 0, stream>>>(A_ws, B_ws, Wt, bout, nrm_g, outp);
}